// Round 6
// baseline (372.561 us; speedup 1.0000x reference)
//
#include <hip/hip_runtime.h>
#include <hip/hip_bf16.h>

typedef __attribute__((ext_vector_type(8))) short short8;       // MFMA A/B frag (8 bf16)
typedef __attribute__((ext_vector_type(4))) float f32x4;        // MFMA C/D frag
typedef __attribute__((ext_vector_type(8))) unsigned short ushort8;

#define LDS_ASYNC16(gsrc, ldst) \
  __builtin_amdgcn_global_load_lds((const __attribute__((address_space(1))) void*)(gsrc), \
                                   (__attribute__((address_space(3))) void*)(ldst), 16, 0, 0)

__device__ __forceinline__ unsigned short f2bf(float f) {
  unsigned int u = __float_as_uint(f);
  unsigned int r = (u + 0x7FFFu + ((u >> 16) & 1u)) >> 16;   // RNE
  return (unsigned short)r;
}
__device__ __forceinline__ float bf2f(unsigned short h) {
  return __uint_as_float((unsigned int)h << 16);
}

// ---------------- fused cast fp32 -> bf16, 5 tensors via z ----------------
__global__ __launch_bounds__(256) void cast5_f32_bf16(
    const float* __restrict__ i0, const float* __restrict__ i1, const float* __restrict__ i2,
    const float* __restrict__ i3, const float* __restrict__ i4,
    unsigned short* __restrict__ out /* 5 contiguous 2Mi-elem regions */) {
  const float* src[5] = {i0, i1, i2, i3, i4};
  int z = blockIdx.z;
  const float* in = src[z];
  size_t i = ((size_t)blockIdx.x * 256 + threadIdx.x) * 8;
  float4 a = *(const float4*)(in + i);
  float4 b = *(const float4*)(in + i + 4);
  ushort8 o;
  o[0] = f2bf(a.x); o[1] = f2bf(a.y); o[2] = f2bf(a.z); o[3] = f2bf(a.w);
  o[4] = f2bf(b.x); o[5] = f2bf(b.y); o[6] = f2bf(b.z); o[7] = f2bf(b.w);
  *(ushort8*)(out + (size_t)z * 2097152 + i) = o;
}

// ---- V transpose (8 heads/group): slot z picks head col block z*512.
// ---- src rows = 2048 tokens (stride 4096). Out: Vt[z][512(d)][2048(k)] ----
__global__ __launch_bounds__(256) void transpose_v(const unsigned short* __restrict__ V,
                                                   unsigned short* __restrict__ Vt) {
  __shared__ unsigned short t[64][72];   // 144B row stride (9x16B) keeps 16B alignment
  int slot = blockIdx.z;
  int k0 = blockIdx.x << 6, d0 = blockIdx.y << 6;
  const unsigned short* src = V + (size_t)k0 * 4096 + slot * 512 + d0;
  int rr = threadIdx.x >> 3;            // 0..31
  int cc = (threadIdx.x & 7) << 3;      // 0,8,..,56
#pragma unroll
  for (int half = 0; half < 64; half += 32) {
    int r = rr + half;
    ushort8 v = *(const ushort8*)(src + (size_t)r * 4096 + cc);
#pragma unroll
    for (int e = 0; e < 8; ++e) t[cc + e][r] = v[e];
  }
  __syncthreads();
  unsigned short* dst = Vt + ((size_t)slot * 512 + d0) * 2048 + k0;
#pragma unroll
  for (int half = 0; half < 64; half += 32) {
    int d = rr + half;
    *(ushort8*)(dst + (size_t)d * 2048 + cc) = *(const ushort8*)&t[d][cc];
  }
}

// ---------------- causal softmax, bf16 scores -> bf16 P in place ----------------
// Row q: reads/writes only k < nW=(q/128+1)*128 (the 128-aligned causal extent);
// masks k>q, writes exact zeros for q<k<nW — exactly the region PV's KCLIP reads.
__global__ __launch_bounds__(256) void softmax_causal_bf16(unsigned short* __restrict__ S) {
  int row = blockIdx.x;          // slot*2048 + q
  int q = row & 2047;
  unsigned short* srow = S + (size_t)row * 2048;
  int n = q + 1;
  int nW = ((q >> 7) + 1) << 7;
  int t = threadIdx.x, wave = t >> 6, lane = t & 63;
  int base = t * 8;
  ushort8 u = {};
  if (base < nW) u = *(const ushort8*)(srow + base);
  float vals[8];
  float m = -1e30f;
#pragma unroll
  for (int e = 0; e < 8; ++e) {
    float v = bf2f(u[e]);
    vals[e] = (base + e < n) ? v : -1e30f;
    m = fmaxf(m, vals[e]);
  }
#pragma unroll
  for (int off = 32; off > 0; off >>= 1) m = fmaxf(m, __shfl_xor(m, off, 64));
  __shared__ float red[8];
  if (lane == 0) red[wave] = m;
  __syncthreads();
  m = fmaxf(fmaxf(red[0], red[1]), fmaxf(red[2], red[3]));
  float s = 0.f;
#pragma unroll
  for (int e = 0; e < 8; ++e) {
    float ex = (base + e < n) ? __expf(vals[e] - m) : 0.f;
    vals[e] = ex; s += ex;
  }
#pragma unroll
  for (int off = 32; off > 0; off >>= 1) s += __shfl_xor(s, off, 64);
  if (lane == 0) red[4 + wave] = s;
  __syncthreads();
  s = red[4] + red[5] + red[6] + red[7];
  float inv = 1.0f / s;
  if (base < nW) {
    ushort8 o;
#pragma unroll
    for (int e = 0; e < 8; ++e) o[e] = f2bf(vals[e] * inv);   // exact zeros for idx >= n
    *(ushort8*)(srow + base) = o;
  }
}

// ---------------- split-K reduce: out = sum of 8 partials ----------------
__global__ __launch_bounds__(256) void reduce_k8(const float4* __restrict__ p,
                                                 float4* __restrict__ out, int n4) {
  int i = blockIdx.x * 256 + threadIdx.x;
  if (i >= n4) return;
  float4 o = p[i];
#pragma unroll
  for (int z = 1; z < 8; ++z) {
    float4 a = p[i + (size_t)z * n4];
    o.x += a.x; o.y += a.y; o.z += a.z; o.w += a.w;
  }
  out[i] = o;
}

// ---------------- bf16 GEMM: C = A * B^T   (A:[M,K] lda, B:[N,K] ldb, row-major bf16) ----------------
// m97 structure: 128x128 tile, BK=64, 4 waves of 64x64, mfma_f32_16x16x32_bf16, global_load_lds w16.
// (R5 lesson: NO XCD swizzle — problem is L3-resident, swizzle doubled QKV FETCH_SIZE.)
template<int OUT_F32, int CSKIP, int KCLIP>
__global__ __launch_bounds__(256, 2) void gemm_bt(
    const unsigned short* __restrict__ A, const unsigned short* __restrict__ B,
    void* __restrict__ C, int K, int lda, int ldb, int ldc, int nH,
    long long sAb, long long sAh, long long sBb, long long sBh,
    long long sCb, long long sCh, float scale)
{
  __shared__ unsigned short As[128 * 64];
  __shared__ unsigned short Bs[128 * 64];
  int m0 = blockIdx.y * 128, n0 = blockIdx.x * 128;
  if (CSKIP && n0 > m0) return;                 // fully-masked causal tile
  int z = blockIdx.z;
  int zb = z / nH, zh = z - zb * nH;
  const unsigned short* Ap = A + (size_t)(zb * sAb + zh * sAh);
  const unsigned short* Bp = B + (size_t)(zb * sBb + zh * sBh);
  size_t coff = (size_t)(zb * sCb + zh * sCh);
  int tid = threadIdx.x;
  int wave = tid >> 6, lane = tid & 63;
  int kEnd = KCLIP ? min(K, m0 + 128) : K;

  int wr = (wave >> 1) * 64, wc = (wave & 1) * 64;  // 2x2 wave grid, 64x64 each
  int lr = lane & 15;
  int lkb = (lane >> 4) * 8;

  f32x4 acc[4][4] = {};

  for (int k0 = 0; k0 < kEnd; k0 += 64) {
#pragma unroll
    for (int it = 0; it < 4; ++it) {
      int g = it * 256 + tid;                  // granule 0..1023 (16B each)
      int r = g >> 3, c = (g & 7) << 3;
      LDS_ASYNC16(Ap + (size_t)(m0 + r) * lda + (k0 + c), As + (size_t)(it * 256 + wave * 64) * 8);
      LDS_ASYNC16(Bp + (size_t)(n0 + r) * ldb + (k0 + c), Bs + (size_t)(it * 256 + wave * 64) * 8);
    }
    __syncthreads();
#pragma unroll
    for (int kk = 0; kk < 64; kk += 32) {
      short8 a[4], b[4];
#pragma unroll
      for (int i = 0; i < 4; ++i)
        a[i] = *(const short8*)(As + (size_t)(wr + i * 16 + lr) * 64 + kk + lkb);
#pragma unroll
      for (int j = 0; j < 4; ++j)
        b[j] = *(const short8*)(Bs + (size_t)(wc + j * 16 + lr) * 64 + kk + lkb);
#pragma unroll
      for (int i = 0; i < 4; ++i)
#pragma unroll
        for (int j = 0; j < 4; ++j)
          acc[i][j] = __builtin_amdgcn_mfma_f32_16x16x32_bf16(a[i], b[j], acc[i][j], 0, 0, 0);
    }
    __syncthreads();
  }

  int orow = (lane >> 4) * 4, ocol = lane & 15;   // C/D: col=lane&15, row=(lane>>4)*4+reg
#pragma unroll
  for (int i = 0; i < 4; ++i)
#pragma unroll
    for (int j = 0; j < 4; ++j)
#pragma unroll
      for (int r = 0; r < 4; ++r) {
        int row = m0 + wr + i * 16 + orow + r;
        int col = n0 + wc + j * 16 + ocol;
        float v = acc[i][j][r] * scale;
        if (OUT_F32) ((float*)C)[coff + (size_t)row * ldc + col] = v;
        else ((unsigned short*)C)[coff + (size_t)row * ldc + col] = f2bf(v);
      }
}

// ---------------- launcher ----------------
extern "C" void kernel_launch(void* const* d_in, const int* in_sizes, int n_in,
                              void* d_out, int out_size, void* d_ws, size_t ws_size,
                              hipStream_t stream) {
  const float* x  = (const float*)d_in[0];
  // d_in[1] = attn_mask (causal; handled analytically)
  const float* Wq = (const float*)d_in[2];
  const float* Wk = (const float*)d_in[3];
  const float* Wv = (const float*)d_in[4];
  const float* Wo = (const float*)d_in[5];

  // workspace layout (MiB, 188 total — proven budget):
  //  [0,4)    xb   bf16 [4096][512]      (dead after proj; Vt overlays [0,16))
  //  [4,16)   Wqkv bf16 [3][4096][512]   (dead after proj)
  //  [16,20)  Wob  bf16 [512][4096]
  //  [20,116) QKV  bf16 [3][4096][4096]  (Q region doubles as attention-out AO)
  //  [116,180) Sc  bf16 [8][2048][2048]  per-batch scores->P   (dead after PV b=1;
  //            out-proj split-K partials fp32 [8][4096][512] = 64 MiB reuse [116,180))
  //  [0,16)   Vt   bf16 [8][512][2048]   per-batch transposed V (post-proj overlay)
  if (ws_size < (size_t)188 * (1 << 20)) return;   // graceful diagnostic (d_out stays 0)

  char* ws = (char*)d_ws;
  unsigned short* xb   = (unsigned short*)(ws);
  unsigned short* Wob  = (unsigned short*)(ws + (size_t)16  * (1 << 20));
  unsigned short* QKV  = (unsigned short*)(ws + (size_t)20  * (1 << 20));
  unsigned short* Sc   = (unsigned short*)(ws + (size_t)116 * (1 << 20));
  unsigned short* Vt   = (unsigned short*)(ws);                      // overlays xb+Wqkv post-proj
  float*          Pp   = (float*)(ws + (size_t)116 * (1 << 20));     // split-K partials (64 MiB)

  const int NEw = 4096 * 512;       // elements per weight matrix / x
  const long long NEm = 4096LL * 4096;  // elements per Q/K/V matrix

  // 1) fused casts: x, Wq, Wk, Wv, Wo -> bf16 [5 regions contiguous from ws+0]
  cast5_f32_bf16<<<dim3(1024, 1, 5), 256, 0, stream>>>(x, Wq, Wk, Wv, Wo, xb);

  // 2) QKV projection: [4096,512] x [4096,512]^T -> [3][4096][4096] bf16
  gemm_bt<0, 0, 0><<<dim3(32, 32, 3), 256, 0, stream>>>(
      xb, xb + NEw, QKV, 512, 512, 512, 4096, 3,
      0LL, 0LL, 0LL, (long long)NEw, 0LL, NEm, 1.0f);

  // 3) attention, 2 groups = batch b, 8 heads each (slot zh = head)
  for (int b = 0; b < 2; ++b) {
    size_t tokOff = (size_t)b * 2048 * 4096;
    const unsigned short* Qb = QKV + tokOff;
    const unsigned short* Kb = QKV + NEm + tokOff;
    const unsigned short* Vb = QKV + 2 * NEm + tokOff;
    unsigned short* AOb = QKV + tokOff;              // AO aliases Q (per-head Q dead after scores)

    // 3a) scores = Q K^T / sqrt(512) -> bf16, causal tile skip
    gemm_bt<0, 1, 0><<<dim3(16, 16, 8), 256, 0, stream>>>(
        Qb, Kb, Sc, 512, 4096, 4096, 2048, 8,
        0LL, 512LL, 0LL, 512LL, 0LL, 2048LL * 2048, 0.04419417382415922f);

    // 3b) V transpose, all 8 heads
    transpose_v<<<dim3(32, 8, 8), 256, 0, stream>>>(Vb, Vt);

    // 3c) softmax (causal) bf16 -> bf16 P in place
    softmax_causal_bf16<<<dim3(8 * 2048), 256, 0, stream>>>(Sc);

    // 3d) O = P @ V via P * Vt^T, k clipped to m0+128
    gemm_bt<0, 0, 1><<<dim3(4, 16, 8), 256, 0, stream>>>(
        Sc, Vt, AOb, 2048, 2048, 2048, 4096, 8,
        0LL, 2048LL * 2048, 0LL, 512LL * 2048, 0LL, 512LL, 1.0f);
  }

  // 4) out-proj split-K=8: partial[z] = AO[:, z*512 +: 512] @ Wob[:, z*512 +: 512]^T
  gemm_bt<1, 0, 0><<<dim3(4, 32, 8), 256, 0, stream>>>(
      QKV, Wob, Pp, 512, 4096, 4096, 512, 8,
      0LL, 512LL, 0LL, 512LL, 0LL, 2097152LL, 1.0f);

  // 5) reduce partials -> fp32 d_out [4096][512]
  reduce_k8<<<dim3(2048), 256, 0, stream>>>((const float4*)Pp, (float4*)d_out, 524288);
}

// Round 8
// 352.925 us; speedup vs baseline: 1.0556x; 1.0556x over previous
//
#include <hip/hip_runtime.h>
#include <hip/hip_bf16.h>

typedef __attribute__((ext_vector_type(8))) short short8;       // MFMA A/B frag (8 bf16)
typedef __attribute__((ext_vector_type(4))) float f32x4;        // MFMA C/D frag
typedef __attribute__((ext_vector_type(8))) unsigned short ushort8;

#define LDS_ASYNC16(gsrc, ldst) \
  __builtin_amdgcn_global_load_lds((const __attribute__((address_space(1))) void*)(gsrc), \
                                   (__attribute__((address_space(3))) void*)(ldst), 16, 0, 0)

__device__ __forceinline__ unsigned short f2bf(float f) {
  unsigned int u = __float_as_uint(f);
  unsigned int r = (u + 0x7FFFu + ((u >> 16) & 1u)) >> 16;   // RNE
  return (unsigned short)r;
}
__device__ __forceinline__ float bf2f(unsigned short h) {
  return __uint_as_float((unsigned int)h << 16);
}

// ---------------- fused cast fp32 -> bf16, 5 tensors via z ----------------
__global__ __launch_bounds__(256) void cast5_f32_bf16(
    const float* __restrict__ i0, const float* __restrict__ i1, const float* __restrict__ i2,
    const float* __restrict__ i3, const float* __restrict__ i4,
    unsigned short* __restrict__ out /* 5 contiguous 2Mi-elem regions */) {
  const float* src[5] = {i0, i1, i2, i3, i4};
  int z = blockIdx.z;
  const float* in = src[z];
  size_t i = ((size_t)blockIdx.x * 256 + threadIdx.x) * 8;
  float4 a = *(const float4*)(in + i);
  float4 b = *(const float4*)(in + i + 4);
  ushort8 o;
  o[0] = f2bf(a.x); o[1] = f2bf(a.y); o[2] = f2bf(a.z); o[3] = f2bf(a.w);
  o[4] = f2bf(b.x); o[5] = f2bf(b.y); o[6] = f2bf(b.z); o[7] = f2bf(b.w);
  *(ushort8*)(out + (size_t)z * 2097152 + i) = o;
}

// ---- V transpose (8 heads/group): slot z picks head col block z*512. ----
__global__ __launch_bounds__(256) void transpose_v(const unsigned short* __restrict__ V,
                                                   unsigned short* __restrict__ Vt) {
  __shared__ unsigned short t[64][72];
  int slot = blockIdx.z;
  int k0 = blockIdx.x << 6, d0 = blockIdx.y << 6;
  const unsigned short* src = V + (size_t)k0 * 4096 + slot * 512 + d0;
  int rr = threadIdx.x >> 3;
  int cc = (threadIdx.x & 7) << 3;
#pragma unroll
  for (int half = 0; half < 64; half += 32) {
    int r = rr + half;
    ushort8 v = *(const ushort8*)(src + (size_t)r * 4096 + cc);
#pragma unroll
    for (int e = 0; e < 8; ++e) t[cc + e][r] = v[e];
  }
  __syncthreads();
  unsigned short* dst = Vt + ((size_t)slot * 512 + d0) * 2048 + k0;
#pragma unroll
  for (int half = 0; half < 64; half += 32) {
    int d = rr + half;
    *(ushort8*)(dst + (size_t)d * 2048 + cc) = *(const ushort8*)&t[d][cc];
  }
}

// ---------------- causal softmax, bf16 scores -> bf16 P in place ----------------
__global__ __launch_bounds__(256) void softmax_causal_bf16(unsigned short* __restrict__ S) {
  int row = blockIdx.x;          // slot*2048 + q
  int q = row & 2047;
  unsigned short* srow = S + (size_t)row * 2048;
  int n = q + 1;
  int nW = ((q >> 7) + 1) << 7;
  int t = threadIdx.x, wave = t >> 6, lane = t & 63;
  int base = t * 8;
  ushort8 u = {};
  if (base < nW) u = *(const ushort8*)(srow + base);
  float vals[8];
  float m = -1e30f;
#pragma unroll
  for (int e = 0; e < 8; ++e) {
    float v = bf2f(u[e]);
    vals[e] = (base + e < n) ? v : -1e30f;
    m = fmaxf(m, vals[e]);
  }
#pragma unroll
  for (int off = 32; off > 0; off >>= 1) m = fmaxf(m, __shfl_xor(m, off, 64));
  __shared__ float red[8];
  if (lane == 0) red[wave] = m;
  __syncthreads();
  m = fmaxf(fmaxf(red[0], red[1]), fmaxf(red[2], red[3]));
  float s = 0.f;
#pragma unroll
  for (int e = 0; e < 8; ++e) {
    float ex = (base + e < n) ? __expf(vals[e] - m) : 0.f;
    vals[e] = ex; s += ex;
  }
#pragma unroll
  for (int off = 32; off > 0; off >>= 1) s += __shfl_xor(s, off, 64);
  if (lane == 0) red[4 + wave] = s;
  __syncthreads();
  s = red[4] + red[5] + red[6] + red[7];
  float inv = 1.0f / s;
  if (base < nW) {
    ushort8 o;
#pragma unroll
    for (int e = 0; e < 8; ++e) o[e] = f2bf(vals[e] * inv);
    *(ushort8*)(srow + base) = o;
  }
}

// ---------------- split-K reduce: out = sum of 4 partials ----------------
__global__ __launch_bounds__(256) void reduce_k4(const float4* __restrict__ p,
                                                 float4* __restrict__ out, int n4) {
  int i = blockIdx.x * 256 + threadIdx.x;
  if (i >= n4) return;
  float4 a = p[i], b = p[i + n4], c = p[i + 2 * n4], d = p[i + 3 * n4];
  float4 o;
  o.x = (a.x + b.x) + (c.x + d.x);
  o.y = (a.y + b.y) + (c.y + d.y);
  o.z = (a.z + b.z) + (c.z + d.z);
  o.w = (a.w + b.w) + (c.w + d.w);
  out[i] = o;
}

// ============ 256x256 deep-pipelined GEMM: C = A * B^T (bf16, row-major) ============
// 512 thr / 8 waves (2M x 4N), BK=64, dbuf LDS 128 KiB, counted vmcnt(8) across raw
// barriers (T4), XOR slot-swizzle slot'=slot^(row&7) realized as inverse-swizzled
// global source + swizzled ds_read (T2, m201 both-sides rule), setprio on MFMA (T5).
template<int OUT_F32, int CSKIP>
__global__ __launch_bounds__(512, 2) void gemm256(
    const unsigned short* __restrict__ A, const unsigned short* __restrict__ B,
    void* __restrict__ C, int K, int lda, int ldb, int ldc, int nH,
    long long sAb, long long sAh, long long sBb, long long sBh,
    long long sCb, long long sCh, float scale)
{
  __shared__ unsigned short As[2][256 * 64];   // 32 KiB per buf
  __shared__ unsigned short Bs[2][256 * 64];   // total 128 KiB
  int m0 = blockIdx.y * 256, n0 = blockIdx.x * 256;
  if (CSKIP && n0 > m0) return;                // fully-masked causal 256-tile
  int z = blockIdx.z;
  int zb = z / nH, zh = z - zb * nH;
  const unsigned short* Ap = A + (size_t)(zb * sAb + zh * sAh);
  const unsigned short* Bp = B + (size_t)(zb * sBb + zh * sBh);
  size_t coff = (size_t)(zb * sCb + zh * sCh);
  int tid = threadIdx.x;
  int wid = tid >> 6, lane = tid & 63;
  int wm = wid >> 2, wn = wid & 3;             // wave grid 2(M) x 4(N); per-wave 128x64
  int lr = lane & 15, hi = lane >> 4;          // frag row / 16B-slot group

  // stage geometry: chunk c = wid*4+g covers rows [c*8, c*8+8); lane -> row c*8+(lane>>3),
  // slot lane&7. Inverse swizzle on the GLOBAL side: fetch data slot (lane&7)^(row&7).
  int srow  = (wid << 5) + (lane >> 3);                 // + g*8
  int swcol = ((lane & 7) ^ ((lane >> 3) & 7)) << 3;    // elem col of lane's 16B

#define STAGE256(t_, buf_) do {                                                   \
    int k0_ = (t_) << 6;                                                          \
    _Pragma("unroll")                                                             \
    for (int g_ = 0; g_ < 4; ++g_) {                                              \
      LDS_ASYNC16(Ap + (size_t)(m0 + srow + g_ * 8) * lda + k0_ + swcol,          \
                  &As[buf_][(wid * 4 + g_) * 512]);                               \
      LDS_ASYNC16(Bp + (size_t)(n0 + srow + g_ * 8) * ldb + k0_ + swcol,          \
                  &Bs[buf_][(wid * 4 + g_) * 512]);                               \
    }                                                                             \
  } while (0)

  // ds_read slot for (kk,hi) at row r: ((kk*4+hi) ^ (r&7)); r&7 == lr&7 everywhere.
  int s0 = (0 + hi) ^ (lr & 7);                // kk=0
  int s1 = (4 + hi) ^ (lr & 7);                // kk=1

  int nt = K >> 6;                             // K-tiles (callers guarantee nt >= 2)
  f32x4 acc[8][4] = {};

  STAGE256(0, 0);
  STAGE256(1, 1);
  asm volatile("s_waitcnt vmcnt(8)" ::: "memory");     // tile 0 landed (tile 1 in flight)
  __builtin_amdgcn_s_barrier();

  for (int t = 0; t < nt; ++t) {
    const unsigned short* Ab = As[t & 1];
    const unsigned short* Bb = Bs[t & 1];
    short8 bf[4][2];
#pragma unroll
    for (int n = 0; n < 4; ++n) {
      int r = wn * 64 + n * 16 + lr;
      bf[n][0] = *(const short8*)(Bb + r * 64 + s0 * 8);
      bf[n][1] = *(const short8*)(Bb + r * 64 + s1 * 8);
    }
#pragma unroll
    for (int p = 0; p < 4; ++p) {
      short8 af[2][2];
#pragma unroll
      for (int mi = 0; mi < 2; ++mi) {
        int r = wm * 128 + (p * 2 + mi) * 16 + lr;
        af[mi][0] = *(const short8*)(Ab + r * 64 + s0 * 8);
        af[mi][1] = *(const short8*)(Ab + r * 64 + s1 * 8);
      }
      __builtin_amdgcn_s_setprio(1);
#pragma unroll
      for (int kk = 0; kk < 2; ++kk)
#pragma unroll
        for (int mi = 0; mi < 2; ++mi)
#pragma unroll
          for (int n = 0; n < 4; ++n)
            acc[p * 2 + mi][n] = __builtin_amdgcn_mfma_f32_16x16x32_bf16(
                af[mi][kk], bf[n][kk], acc[p * 2 + mi][n], 0, 0, 0);
      __builtin_amdgcn_s_setprio(0);
    }
    if (t + 1 < nt) {
      __builtin_amdgcn_s_barrier();                    // all waves done reading buf t&1
      if (t + 2 < nt) {
        STAGE256(t + 2, t & 1);
        asm volatile("s_waitcnt vmcnt(8)" ::: "memory"); // tile t+1 landed; t+2 in flight
      } else {
        asm volatile("s_waitcnt vmcnt(0)" ::: "memory"); // drain (penultimate iter only)
      }
      __builtin_amdgcn_s_barrier();
    }
  }
#undef STAGE256

#pragma unroll
  for (int m = 0; m < 8; ++m)
#pragma unroll
    for (int n = 0; n < 4; ++n)
#pragma unroll
      for (int r = 0; r < 4; ++r) {
        int row = m0 + wm * 128 + m * 16 + hi * 4 + r;
        int col = n0 + wn * 64 + n * 16 + lr;
        float v = acc[m][n][r] * scale;
        if (OUT_F32) ((float*)C)[coff + (size_t)row * ldc + col] = v;
        else ((unsigned short*)C)[coff + (size_t)row * ldc + col] = f2bf(v);
      }
}

// ---------------- m97-structure 128x128 GEMM (proven engine, PV / out-proj) ----------------
template<int OUT_F32, int CSKIP, int KCLIP>
__global__ __launch_bounds__(256, 2) void gemm_bt(
    const unsigned short* __restrict__ A, const unsigned short* __restrict__ B,
    void* __restrict__ C, int K, int lda, int ldb, int ldc, int nH,
    long long sAb, long long sAh, long long sBb, long long sBh,
    long long sCb, long long sCh, float scale)
{
  __shared__ unsigned short As[128 * 64];
  __shared__ unsigned short Bs[128 * 64];
  int m0 = blockIdx.y * 128, n0 = blockIdx.x * 128;
  if (CSKIP && n0 > m0) return;
  int z = blockIdx.z;
  int zb = z / nH, zh = z - zb * nH;
  const unsigned short* Ap = A + (size_t)(zb * sAb + zh * sAh);
  const unsigned short* Bp = B + (size_t)(zb * sBb + zh * sBh);
  size_t coff = (size_t)(zb * sCb + zh * sCh);
  int tid = threadIdx.x;
  int wave = tid >> 6, lane = tid & 63;
  int kEnd = KCLIP ? min(K, m0 + 128) : K;

  int wr = (wave >> 1) * 64, wc = (wave & 1) * 64;
  int lr = lane & 15;
  int lkb = (lane >> 4) * 8;

  f32x4 acc[4][4] = {};

  for (int k0 = 0; k0 < kEnd; k0 += 64) {
#pragma unroll
    for (int it = 0; it < 4; ++it) {
      int g = it * 256 + tid;
      int r = g >> 3, c = (g & 7) << 3;
      LDS_ASYNC16(Ap + (size_t)(m0 + r) * lda + (k0 + c), As + (size_t)(it * 256 + wave * 64) * 8);
      LDS_ASYNC16(Bp + (size_t)(n0 + r) * ldb + (k0 + c), Bs + (size_t)(it * 256 + wave * 64) * 8);
    }
    __syncthreads();
#pragma unroll
    for (int kk = 0; kk < 64; kk += 32) {
      short8 a[4], b[4];
#pragma unroll
      for (int i = 0; i < 4; ++i)
        a[i] = *(const short8*)(As + (size_t)(wr + i * 16 + lr) * 64 + kk + lkb);
#pragma unroll
      for (int j = 0; j < 4; ++j)
        b[j] = *(const short8*)(Bs + (size_t)(wc + j * 16 + lr) * 64 + kk + lkb);
#pragma unroll
      for (int i = 0; i < 4; ++i)
#pragma unroll
        for (int j = 0; j < 4; ++j)
          acc[i][j] = __builtin_amdgcn_mfma_f32_16x16x32_bf16(a[i], b[j], acc[i][j], 0, 0, 0);
    }
    __syncthreads();
  }

  int orow = (lane >> 4) * 4, ocol = lane & 15;
#pragma unroll
  for (int i = 0; i < 4; ++i)
#pragma unroll
    for (int j = 0; j < 4; ++j)
#pragma unroll
      for (int r = 0; r < 4; ++r) {
        int row = m0 + wr + i * 16 + orow + r;
        int col = n0 + wc + j * 16 + ocol;
        float v = acc[i][j][r] * scale;
        if (OUT_F32) ((float*)C)[coff + (size_t)row * ldc + col] = v;
        else ((unsigned short*)C)[coff + (size_t)row * ldc + col] = f2bf(v);
      }
}

// ---------------- launcher ----------------
extern "C" void kernel_launch(void* const* d_in, const int* in_sizes, int n_in,
                              void* d_out, int out_size, void* d_ws, size_t ws_size,
                              hipStream_t stream) {
  const float* x  = (const float*)d_in[0];
  // d_in[1] = attn_mask (causal; handled analytically)
  const float* Wq = (const float*)d_in[2];
  const float* Wk = (const float*)d_in[3];
  const float* Wv = (const float*)d_in[4];
  const float* Wo = (const float*)d_in[5];

  // workspace layout (MiB, 188 total — proven budget):
  //  [0,4)    xb   bf16 [4096][512]      (dead after proj; Vt overlays [0,16))
  //  [4,16)   Wqkv bf16 [3][4096][512]   (dead after proj)
  //  [16,20)  Wob  bf16 [512][4096]
  //  [20,116) QKV  bf16 [3][4096][4096]  (Q region doubles as attention-out AO)
  //  [116,180) Sc  bf16 [8][2048][2048]  per-batch scores->P (dead after PV b=1;
  //            out-proj split-K4 partials fp32 [4][4096][512] = 32 MiB reuse)
  //  [0,16)   Vt   bf16 [8][512][2048]   per-batch transposed V (post-proj overlay)
  if (ws_size < (size_t)188 * (1 << 20)) return;

  char* ws = (char*)d_ws;
  unsigned short* xb   = (unsigned short*)(ws);
  unsigned short* Wob  = (unsigned short*)(ws + (size_t)16  * (1 << 20));
  unsigned short* QKV  = (unsigned short*)(ws + (size_t)20  * (1 << 20));
  unsigned short* Sc   = (unsigned short*)(ws + (size_t)116 * (1 << 20));
  unsigned short* Vt   = (unsigned short*)(ws);
  float*          Pp   = (float*)(ws + (size_t)116 * (1 << 20));

  const int NEw = 4096 * 512;
  const long long NEm = 4096LL * 4096;

  // 1) fused casts
  cast5_f32_bf16<<<dim3(1024, 1, 5), 256, 0, stream>>>(x, Wq, Wk, Wv, Wo, xb);

  // 2) QKV projection on the 256² deep-pipelined engine: K=512 (8 K-tiles)
  gemm256<0, 0><<<dim3(16, 16, 3), 512, 0, stream>>>(
      xb, xb + NEw, QKV, 512, 512, 512, 4096, 3,
      0LL, 0LL, 0LL, (long long)NEw, 0LL, NEm, 1.0f);

  // 3) attention, per batch (8 heads via z)
  for (int b = 0; b < 2; ++b) {
    size_t tokOff = (size_t)b * 2048 * 4096;
    const unsigned short* Qb = QKV + tokOff;
    const unsigned short* Kb = QKV + NEm + tokOff;
    const unsigned short* Vb = QKV + 2 * NEm + tokOff;
    unsigned short* AOb = QKV + tokOff;              // AO aliases Q

    // 3a) scores = Q K^T / sqrt(512) -> bf16, causal 256-tile skip, 256² engine
    gemm256<0, 1><<<dim3(8, 8, 8), 512, 0, stream>>>(
        Qb, Kb, Sc, 512, 4096, 4096, 2048, 8,
        0LL, 512LL, 0LL, 512LL, 0LL, 2048LL * 2048, 0.04419417382415922f);

    // 3b) V transpose
    transpose_v<<<dim3(32, 8, 8), 256, 0, stream>>>(Vb, Vt);

    // 3c) softmax (causal) bf16 -> bf16 P in place
    softmax_causal_bf16<<<dim3(8 * 2048), 256, 0, stream>>>(Sc);

    // 3d) O = P @ V via P * Vt^T, k clipped to m0+128 (m97 engine, 512 blocks)
    gemm_bt<0, 0, 1><<<dim3(4, 16, 8), 256, 0, stream>>>(
        Sc, Vt, AOb, 2048, 2048, 2048, 4096, 8,
        0LL, 2048LL * 2048, 0LL, 512LL * 2048, 0LL, 512LL, 1.0f);
  }

  // 4) out-proj split-K=4 (m97 engine; proven config)
  gemm_bt<1, 0, 0><<<dim3(4, 32, 4), 256, 0, stream>>>(
      QKV, Wob, Pp, 1024, 4096, 4096, 512, 4,
      0LL, 1024LL, 0LL, 1024LL, 0LL, 2097152LL, 1.0f);

  // 5) reduce partials -> fp32 d_out
  reduce_k4<<<dim3(2048), 256, 0, stream>>>((const float4*)Pp, (float4*)d_out, 524288);
}